// Round 13
// baseline (383.377 us; speedup 1.0000x reference)
//
#include <hip/hip_runtime.h>

// WindowAttentionGlobal on MI355X — round 20: kill xbf + vector chanmean.
// Round-19: tap-sharing delivered (370us); noise band established at ±10us ->
// bundle two traffic eliminations: (1) gemm_qkv stages A directly from fp32 x
// (window-order rows are 49-contiguous x-rows; hw RNE cast == manual f2b) so
// prep no longer writes xbf (-25MB w, -25MB cold r); (2) chanmean re-applied
// as wave-wide ushort4 row reads (round-18 form; prior +12 was noise).

#define DEV static __device__ __forceinline__
typedef unsigned short u16;
typedef unsigned int u32;
typedef __attribute__((ext_vector_type(8))) short short8;
typedef __attribute__((ext_vector_type(4))) float f32x4;

DEV float b2f(u16 s) { union { u32 i; float f; } u; u.i = ((u32)s) << 16; return u.f; }
DEV u16 f2b(float f) {
    union { float f; u32 i; } u; u.f = f;
    u32 x = u.i;
    return (u16)((x + 0x7fffu + ((x >> 16) & 1u)) >> 16);
}
DEV u16 f2b_hw(float f) {
    __bf16 b = (__bf16)f;
    return __builtin_bit_cast(u16, b);
}
DEV float gelu_f(float x) { return 0.5f * x * (1.0f + erff(x * 0.70710678118654752440f)); }

// row r (window order) -> x flat base offset
DEV size_t x_rowbase(int r) {
    int b_ = r / 98, n = r % 98;
    int bb = b_ >> 6, gxi = (b_ >> 3) & 7, gyi = b_ & 7;
    int m = n / 49, rr = n % 49, w1 = rr / 7, w2 = rr % 7;
    return (((((size_t)(bb * 2 + m) * 8 + gxi) * 8 + gyi) * 7 + w1) * 7 + w2) * 256;
}

// ---------------- prep: linear x read -> xg0 (NHWC) ----------------
__global__ __launch_bounds__(256) void k_prep_xg(const float* __restrict__ x, float* __restrict__ xg0) {
    int t = threadIdx.x;
    int s = blockIdx.x * 4 + (t >> 6);           // x-linear row, 0..50175
    int c4 = (t & 63) << 2;
    int w2 = s % 7, t1 = s / 7;
    int w1 = t1 % 7, t2 = t1 / 7;
    int gy = t2 % 8, t3 = t2 / 8;
    int gx = t3 % 8, nm = t3 / 8;
    int rg = nm * 3136 + (gx * 7 + w1) * 56 + gy * 7 + w2;
    float4 v = *(const float4*)(x + (size_t)s * 256 + c4);
    *(float4*)(xg0 + (size_t)rg * 256 + c4) = v;
}

// ---------------- prep: weights to bf16 + dw transpose ----------------
__global__ __launch_bounds__(256) void k_prep_w(const float* __restrict__ wq, const float* __restrict__ wo,
                                                const float* __restrict__ pw1, const float* __restrict__ pw2,
                                                const float* __restrict__ dw1, const float* __restrict__ dw2,
                                                u16* __restrict__ wqt, u16* __restrict__ wot,
                                                u16* __restrict__ pwb1, u16* __restrict__ pwb2,
                                                float* __restrict__ dwt1, float* __restrict__ dwt2) {
    int bid = blockIdx.x, t = threadIdx.x;
    if (bid < 512) {
        wqt[bid * 256 + t] = f2b(wq[(size_t)t * 512 + bid]);
    } else if (bid < 768) {
        int n = bid - 512;
        wot[n * 256 + t] = f2b(wo[(size_t)t * 256 + n]);
    } else if (bid < 1024) {
        int n = bid - 768;
        pwb1[n * 256 + t] = f2b(pw1[(size_t)n * 256 + t]);
    } else if (bid < 1280) {
        int n = bid - 1024;
        pwb2[n * 256 + t] = f2b(pw2[(size_t)n * 256 + t]);
    } else if (bid < 1289) {
        int k = bid - 1280;
        dwt1[k * 256 + t] = dw1[t * 9 + k];
    } else {
        int k = bid - 1289;
        dwt2[k * 256 + t] = dw2[t * 9 + k];
    }
}

// ---------------- precompute attention bias: biasf[h][i][j] (j padded to 112, pad = -1e38) ----------------
__global__ __launch_bounds__(256) void k_bias(const float* __restrict__ rpe, float* __restrict__ biasf) {
    int u = blockIdx.x * 256 + threadIdx.x;      // 8*98*112 = 87808 exactly (343 blocks)
    int h = u / 10976, rem = u % 10976;
    int i = rem / 112, j = rem % 112;
    float v;
    if (j >= 98) {
        v = -1.0e38f;
    } else {
        int mi = (i >= 49), ri = i - 49 * mi, ai = ri / 7, bi = ri % 7;
        int mj = (j >= 49), rj = j - 49 * mj, aj = rj / 7, bj = rj % 7;
        int idx = ((mi - mj + 1) * 13 + (ai - aj + 6)) * 13 + (bi - bj + 6);
        v = rpe[idx * 8 + h];
    }
    biasf[u] = v;
}

// ---------------- MFMA GEMM core (A[M][256] @ Bt[N][256]^T), 128x128 tile ----------------
DEV void gemm_tile(const u16* __restrict__ A, const u16* __restrict__ Bt,
                   int r0, int n0, int t, f32x4 acc[4][4],
                   u16 (*A_l)[72], u16 (*B_l)[72]) {
    int w = t >> 6, l = t & 63;
    int quad = l >> 4, lm = l & 15;
    int wm = (w & 1) * 64, wn = (w >> 1) * 64;
    for (int k0 = 0; k0 < 256; k0 += 64) {
        __syncthreads();
        #pragma unroll
        for (int i = 0; i < 4; i++) {
            int u = t + (i << 8);
            int row = u >> 3, k8 = (u & 7) << 3;
            *(uint4*)&A_l[row][k8] = *(const uint4*)(A + (size_t)(r0 + row) * 256 + k0 + k8);
            *(uint4*)&B_l[row][k8] = *(const uint4*)(Bt + (size_t)(n0 + row) * 256 + k0 + k8);
        }
        __syncthreads();
        #pragma unroll
        for (int kk = 0; kk < 64; kk += 32) {
            short8 af[4], bf[4];
            #pragma unroll
            for (int i = 0; i < 4; i++) af[i] = *(const short8*)&A_l[wm + 16 * i + lm][kk + quad * 8];
            #pragma unroll
            for (int j = 0; j < 4; j++) bf[j] = *(const short8*)&B_l[wn + 16 * j + lm][kk + quad * 8];
            #pragma unroll
            for (int i = 0; i < 4; i++)
                #pragma unroll
                for (int j = 0; j < 4; j++)
                    acc[i][j] = __builtin_amdgcn_mfma_f32_16x16x32_bf16(af[i], bf[j], acc[i][j], 0, 0, 0);
        }
    }
}

// qkv GEMM — A staged directly from fp32 x (window-order rows), writes kv [sel][head][row][32]
__global__ __launch_bounds__(256, 2) void k_gemm_qkv(const float* __restrict__ X, const u16* __restrict__ Bt,
                                                     const float* __restrict__ bias, u16* __restrict__ C) {
    __shared__ u16 A_l[128][72];
    __shared__ u16 B_l[128][72];
    int r0 = blockIdx.x * 128, n0 = blockIdx.y * 128;
    int t = threadIdx.x;
    int w = t >> 6, l = t & 63;
    int quad = l >> 4, lm = l & 15;
    int wm = (w & 1) * 64, wn = (w >> 1) * 64;
    // hoist per-thread A source bases (4 rows/thread, constant across k0)
    size_t abase[4];
    #pragma unroll
    for (int i = 0; i < 4; i++) {
        int u = t + (i << 8);
        abase[i] = x_rowbase(r0 + (u >> 3)) + ((u & 7) << 3);
    }
    f32x4 acc[4][4] = {};
    for (int k0 = 0; k0 < 256; k0 += 64) {
        __syncthreads();
        #pragma unroll
        for (int i = 0; i < 4; i++) {
            int u = t + (i << 8);
            int row = u >> 3, k8 = (u & 7) << 3;
            const float* s = X + abase[i] + k0;
            float4 va = *(const float4*)s;
            float4 vb = *(const float4*)(s + 4);
            short8 pk;
            pk[0] = (short)f2b_hw(va.x); pk[1] = (short)f2b_hw(va.y);
            pk[2] = (short)f2b_hw(va.z); pk[3] = (short)f2b_hw(va.w);
            pk[4] = (short)f2b_hw(vb.x); pk[5] = (short)f2b_hw(vb.y);
            pk[6] = (short)f2b_hw(vb.z); pk[7] = (short)f2b_hw(vb.w);
            *(short8*)&A_l[row][k8] = pk;
            *(uint4*)&B_l[row][k8] = *(const uint4*)(Bt + (size_t)(n0 + row) * 256 + k0 + k8);
        }
        __syncthreads();
        #pragma unroll
        for (int kk = 0; kk < 64; kk += 32) {
            short8 af[4], bf[4];
            #pragma unroll
            for (int i = 0; i < 4; i++) af[i] = *(const short8*)&A_l[wm + 16 * i + lm][kk + quad * 8];
            #pragma unroll
            for (int j = 0; j < 4; j++) bf[j] = *(const short8*)&B_l[wn + 16 * j + lm][kk + quad * 8];
            #pragma unroll
            for (int i = 0; i < 4; i++)
                #pragma unroll
                for (int j = 0; j < 4; j++)
                    acc[i][j] = __builtin_amdgcn_mfma_f32_16x16x32_bf16(af[i], bf[j], acc[i][j], 0, 0, 0);
        }
    }
    float bj[4];
    #pragma unroll
    for (int j = 0; j < 4; j++) bj[j] = bias[n0 + wn + 16 * j + lm];
    #pragma unroll
    for (int i = 0; i < 4; i++) {
        int rbase = r0 + wm + 16 * i + quad * 4;
        #pragma unroll
        for (int reg = 0; reg < 4; reg++) {
            int row = rbase + reg;
            #pragma unroll
            for (int j = 0; j < 4; j++) {
                int c0 = n0 + wn + 16 * j;                  // 16-aligned, within one head slab
                int slab = c0 >> 5;                          // sel*8 + head
                int dd = c0 & 31;                            // 0 or 16
                C[((size_t)slab * 50176 + row) * 32 + dd + lm] = f2b(acc[i][j][reg] + bj[j]);
            }
        }
    }
}

// toout GEMM + permutation
__global__ __launch_bounds__(256, 2) void k_gemm_toout(const u16* __restrict__ A, const u16* __restrict__ Bt,
                                                       float* __restrict__ outp) {
    __shared__ u16 A_l[128][72];
    __shared__ u16 B_l[128][72];
    int r0 = blockIdx.x * 128, n0 = blockIdx.y * 128;
    int t = threadIdx.x;
    f32x4 acc[4][4] = {};
    gemm_tile(A, Bt, r0, n0, t, acc, A_l, B_l);
    int w = t >> 6, l = t & 63;
    int quad = l >> 4, lm = l & 15;
    int wm = (w & 1) * 64, wn = (w >> 1) * 64;
    #pragma unroll
    for (int i = 0; i < 4; i++) {
        int rbase = r0 + wm + 16 * i + quad * 4;
        #pragma unroll
        for (int reg = 0; reg < 4; reg++) {
            size_t ob = x_rowbase(rbase + reg);
            #pragma unroll
            for (int j = 0; j < 4; j++)
                outp[ob + n0 + wn + 16 * j + lm] = acc[i][j][reg];
        }
    }
}

// ---------------- per-image SE-scaled weights: pwsc[n][co][ci] = pw[co][ci]*u[n][ci] ----------------
__global__ __launch_bounds__(256) void k_scale_w(const u16* __restrict__ pwb, const float* __restrict__ ubuf,
                                                 u16* __restrict__ pwsc) {
    int b = blockIdx.x;              // 4096 = 16n * 256co
    int n = b >> 8, co = b & 255;
    int ci = threadIdx.x;
    pwsc[((size_t)b) * 256 + ci] = f2b(b2f(pwb[co * 256 + ci]) * ubuf[n * 256 + ci]);
}

// ---------------- MFMA pointwise conv (NHWC, 1D grid, XCD-chunked) ----------------
template<int HW>
__global__ __launch_bounds__(256, 2) void k_pwconv_mfma_t(const u16* __restrict__ yT, const u16* __restrict__ pwsc,
                                                          float* __restrict__ base) {
    __shared__ u16 A_l[128][72];
    __shared__ u16 B_l[128][72];
    const int PX = (HW + 127) >> 7;
    int cpx = gridDim.x >> 3;
    int bid = (blockIdx.x & 7) * cpx + (blockIdx.x >> 3);
    int c0 = (bid & 1) * 128;
    int rem = bid >> 1;
    int p0 = (rem % PX) * 128;
    int n  = rem / PX;
    int t = threadIdx.x;
    const u16* A = yT + (size_t)n * HW * 256;
    const u16* Bt = pwsc + (size_t)n * 65536;
    f32x4 acc[4][4] = {};
    gemm_tile(A, Bt, p0, c0, t, acc, A_l, B_l);   // OOB A rows read garbage -> discarded rows
    int w = t >> 6, l = t & 63;
    int quad = l >> 4, lm = l & 15;
    int wm = (w & 1) * 64, wn = (w >> 1) * 64;
    #pragma unroll
    for (int i = 0; i < 4; i++) {
        int pb = p0 + wm + 16 * i + quad * 4;
        #pragma unroll
        for (int reg = 0; reg < 4; reg++) {
            int p = pb + reg;
            if (p < HW) {
                size_t rowb = ((size_t)n * HW + p) * 256;
                #pragma unroll
                for (int j = 0; j < 4; j++)
                    base[rowb + c0 + wn + 16 * j + lm] += acc[i][j][reg];
            }
        }
    }
}

// ---------------- MFMA window attention per (window b_, head h), 4 waves ----------------
// kv: [sel(2)][head(8)][row(50176)][32], qg: [b(8)][head(8)][row(98)][32]
// Swapped QK^T: acc = mfma(K, Q) -> lane lm holds q-row (m0+lm); j = t6*16+quad*4+reg.
__global__ __launch_bounds__(256, 4) void k_attn_mfma(const u16* __restrict__ kv, const u16* __restrict__ qg,
                                                      const float* __restrict__ biasf, u16* __restrict__ ao) {
    __shared__ u16 K_l[112][40];
    __shared__ u16 Vt_l[32][136];
    __shared__ u16 P_l[4][16][136];
    int b_ = blockIdx.x, h = blockIdx.y;
    int bb = b_ >> 6;
    int t = threadIdx.x;

    const u16* kq = kv + ((size_t)h * 50176 + (size_t)b_ * 98) * 32;          // sel=0 slab
    const u16* kvv = kv + ((size_t)(8 + h) * 50176 + (size_t)b_ * 98) * 32;   // sel=1 slab
    const u16* qgn = qg + ((size_t)(bb * 8 + h) * 98) * 32;

    // K staging: contiguous 16B/lane loads
    for (int u = t; u < 392; u += 256) {
        int row = u >> 2, q8 = (u & 3) << 3;
        *(short8*)&K_l[row][q8] = *(const short8*)(kq + u * 8);
    }
    for (int u = t; u < 224; u += 256) {
        int row = 98 + (u >> 4), c2 = (u & 15) << 1;
        *(u32*)&K_l[row][c2] = 0;
    }
    // V staging: contiguous short8 loads, transposed scatter into Vt_l
    for (int u = t; u < 392; u += 256) {
        int j = u >> 2, c = u & 3;
        short8 v = *(const short8*)(kvv + u * 8);
        #pragma unroll
        for (int e = 0; e < 8; e++) Vt_l[c * 8 + e][j] = (u16)v[e];
    }
    for (int u = t; u < 1216; u += 256) {
        int d = u / 38, c = 98 + u % 38;
        Vt_l[d][c] = 0;
    }
    for (int u = t; u < 1536; u += 256) {
        int wv = u / 384, rem = u % 384;
        P_l[wv][rem / 24][112 + rem % 24] = 0;
    }
    __syncthreads();

    int w = t >> 6, l = t & 63;
    int quad = l >> 4, lm = l & 15;
    const float scale = 0.17677669529663688f;

    #pragma unroll
    for (int half = 0; half < 2; half++) {
        int mt = w + 4 * half;
        if (mt >= 7) break;
        int m0 = mt * 16;
        int qrow = m0 + lm; qrow = (qrow < 98) ? qrow : 97;
        // bias: i = qrow (lane-local), j = t6*16 + quad*4 + reg -> 7 float4 loads
        const float* bp = biasf + (size_t)(h * 98 + qrow) * 112 + quad * 4;
        f32x4 b4[7];
        #pragma unroll
        for (int t6 = 0; t6 < 7; t6++) b4[t6] = *(const f32x4*)(bp + t6 * 16);
        short8 aq = *(const short8*)(qgn + qrow * 32 + quad * 8);
        f32x4 acc[7] = {};
        #pragma unroll
        for (int t6 = 0; t6 < 7; t6++) {
            short8 bk = *(const short8*)&K_l[t6 * 16 + lm][quad * 8];
            acc[t6] = __builtin_amdgcn_mfma_f32_16x16x32_bf16(bk, aq, acc[t6], 0, 0, 0);  // swapped
        }
        // softmax over lane-local row (28 values) + 2-shuffle cross-quad reduce
        float mx = -3.0e38f;
        #pragma unroll
        for (int t6 = 0; t6 < 7; t6++) {
            #pragma unroll
            for (int reg = 0; reg < 4; reg++) {
                float s = acc[t6][reg] * scale + b4[t6][reg];
                acc[t6][reg] = s;
                mx = fmaxf(mx, s);
            }
        }
        mx = fmaxf(mx, __shfl_xor(mx, 16));
        mx = fmaxf(mx, __shfl_xor(mx, 32));
        float sum = 0.f;
        #pragma unroll
        for (int t6 = 0; t6 < 7; t6++) {
            #pragma unroll
            for (int reg = 0; reg < 4; reg++) {
                float e = __expf(acc[t6][reg] - mx);
                acc[t6][reg] = e; sum += e;
            }
        }
        sum += __shfl_xor(sum, 16);
        sum += __shfl_xor(sum, 32);
        float inv = 1.0f / sum;
        #pragma unroll
        for (int t6 = 0; t6 < 7; t6++) {
            ushort4 s4;
            s4.x = f2b_hw(acc[t6][0] * inv);
            s4.y = f2b_hw(acc[t6][1] * inv);
            s4.z = f2b_hw(acc[t6][2] * inv);
            s4.w = f2b_hw(acc[t6][3] * inv);
            *(ushort4*)&P_l[w][lm][t6 * 16 + quad * 4] = s4;
        }
        __builtin_amdgcn_s_waitcnt(0);   // lgkmcnt(0): P_l writes visible wave-locally
        short8 pa[4];
        #pragma unroll
        for (int kc = 0; kc < 4; kc++)
            pa[kc] = *(const short8*)&P_l[w][lm][kc * 32 + quad * 8];
        #pragma unroll
        for (int nt = 0; nt < 2; nt++) {
            f32x4 oacc = {};
            #pragma unroll
            for (int kc = 0; kc < 4; kc++) {
                short8 bv = *(const short8*)&Vt_l[nt * 16 + lm][kc * 32 + quad * 8];
                oacc = __builtin_amdgcn_mfma_f32_16x16x32_bf16(pa[kc], bv, oacc, 0, 0, 0);
            }
            #pragma unroll
            for (int reg = 0; reg < 4; reg++) {
                int orow = m0 + quad * 4 + reg;
                if (orow < 98)
                    ao[((size_t)(b_ * 98 + orow)) * 256 + h * 32 + nt * 16 + lm] = f2b_hw(oacc[reg]);
            }
        }
    }
}

// ---------------- depthwise 3x3 pad1 + GELU (NHWC, 2 pixels x 4ch/thread, XCD-swizzled) -> bf16 ----------------
template<int HW, int WW>
__global__ __launch_bounds__(256) void k_dwconv_t(const float* __restrict__ in, const float* __restrict__ dwT,
                                                  u16* __restrict__ out) {
    const int HP = HW / 2;                       // pixel pairs per image
    const int WP = WW / 2;
    int cpx = gridDim.x >> 3;
    int bid = (blockIdx.x & 7) * cpx + (blockIdx.x >> 3);
    int idx = bid * 256 + threadIdx.x;           // over 16*HP*64
    int c4 = (idx & 63) << 2;
    int pp = (idx >> 6) % HP;
    int n  = (idx >> 6) / HP;
    int i  = pp / WP, jp = (pp % WP) * 2;        // pixels (i,jp), (i,jp+1)
    const float* base = in + (size_t)n * HW * 256 + c4;
    f32x4 w0[3], w1[3], w2[3];
    #pragma unroll
    for (int dy = 0; dy < 3; dy++) {
        w0[dy] = *(const f32x4*)(dwT + (dy * 3 + 0) * 256 + c4);
        w1[dy] = *(const f32x4*)(dwT + (dy * 3 + 1) * 256 + c4);
        w2[dy] = *(const f32x4*)(dwT + (dy * 3 + 2) * 256 + c4);
    }
    f32x4 acc0 = {}, acc1 = {};
    #pragma unroll
    for (int dy = 0; dy < 3; dy++) {
        int y = i + dy - 1;
        if (y < 0 || y >= WW) continue;
        const float* rowb = base + (size_t)(y * WW) * 256;
        f32x4 v1 = *(const f32x4*)(rowb + (size_t)jp * 256);
        f32x4 v2 = *(const f32x4*)(rowb + (size_t)(jp + 1) * 256);
        f32x4 v0 = (jp > 0) ? *(const f32x4*)(rowb + (size_t)(jp - 1) * 256) : (f32x4){};
        f32x4 v3 = (jp + 2 < WW) ? *(const f32x4*)(rowb + (size_t)(jp + 2) * 256) : (f32x4){};
        acc0 += v0 * w0[dy] + v1 * w1[dy] + v2 * w2[dy];
        acc1 += v1 * w0[dy] + v2 * w1[dy] + v3 * w2[dy];
    }
    ushort4 o0, o1;
    o0.x = f2b(gelu_f(acc0[0])); o0.y = f2b(gelu_f(acc0[1]));
    o0.z = f2b(gelu_f(acc0[2])); o0.w = f2b(gelu_f(acc0[3]));
    o1.x = f2b(gelu_f(acc1[0])); o1.y = f2b(gelu_f(acc1[1]));
    o1.z = f2b(gelu_f(acc1[2])); o1.w = f2b(gelu_f(acc1[3]));
    size_t ob = ((size_t)n * HW + (size_t)i * WW + jp) * 256 + c4;
    *(ushort4*)(out + ob) = o0;
    *(ushort4*)(out + ob + 256) = o1;
}

// ---------------- channel sums (NHWC, vectorized): sbuf[n][c] += partial ----------------
// wave rr reads full 512B rows (ushort4/lane), strided by 4; LDS 4->1 reduce; 256 atomics/block.
template<int HW>
__global__ __launch_bounds__(256) void k_chanmean_t(const u16* __restrict__ y, float* __restrict__ sbuf) {
    __shared__ float4 red[256];
    int n = blockIdx.x, sl = blockIdx.y;         // 16 slices
    int t = threadIdx.x;
    const int PP = HW / 16;
    int c4 = (t & 63) << 2;
    int rr = t >> 6;
    const u16* base = y + ((size_t)n * HW + sl * PP) * 256 + c4;
    float sx = 0.f, sy = 0.f, sz = 0.f, sw = 0.f;
    for (int p = rr; p < PP; p += 4) {
        ushort4 v = *(const ushort4*)(base + (size_t)p * 256);
        sx += b2f(v.x); sy += b2f(v.y); sz += b2f(v.z); sw += b2f(v.w);
    }
    float4 r; r.x = sx; r.y = sy; r.z = sz; r.w = sw;
    red[t] = r;
    __syncthreads();
    if (t < 64) {
        float4 a = red[t], b = red[t + 64], c = red[t + 128], d = red[t + 192];
        float* sp = sbuf + n * 256 + (t << 2);
        atomicAdd(sp + 0, a.x + b.x + c.x + d.x);
        atomicAdd(sp + 1, a.y + b.y + c.y + d.y);
        atomicAdd(sp + 2, a.z + b.z + c.z + d.z);
        atomicAdd(sp + 3, a.w + b.w + c.w + d.w);
    }
}

// ---------------- SE MLP (1/HW folded into se1) ----------------
__global__ __launch_bounds__(256) void k_se1(const float* __restrict__ sbuf, const float* __restrict__ se1,
                                             float* __restrict__ tbuf, float invHW) {
    int o = blockIdx.x * 256 + threadIdx.x;
    int n = o >> 6, j = o & 63;
    const float* srow = sbuf + n * 256;
    float acc = 0.f;
    for (int c = 0; c < 256; c++) acc += srow[c] * se1[c * 64 + j];
    tbuf[o] = gelu_f(acc * invHW);
}
__global__ __launch_bounds__(256) void k_se2(const float* __restrict__ tbuf, const float* __restrict__ se2,
                                             float* __restrict__ ubuf) {
    int o = blockIdx.x * 256 + threadIdx.x;
    int n = o >> 8, co = o & 255;
    const float* trow = tbuf + n * 64;
    float acc = 0.f;
    for (int j = 0; j < 64; j++) acc += trow[j] * se2[j * 256 + co];
    ubuf[o] = 1.0f / (1.0f + __expf(-acc));
}

// ---------------- maxpool 3x3 s2 p1 (NHWC, float4/thread, XCD-swizzled) ----------------
template<int HI>
__global__ __launch_bounds__(256) void k_maxpool_t(const float* __restrict__ in, float* __restrict__ out) {
    const int HO = HI / 2;
    int cpx = gridDim.x >> 3;
    int bid = (blockIdx.x & 7) * cpx + (blockIdx.x >> 3);
    int idx = bid * 256 + threadIdx.x;           // over 16*HO*HO*64
    int c4 = (idx & 63) << 2;
    int pp = (idx >> 6) % (HO * HO);
    int n = (idx >> 6) / (HO * HO);
    int j = pp % HO, i = pp / HO;
    const float* base = in + (size_t)n * HI * HI * 256 + c4;
    float mx = -3.0e38f, my = -3.0e38f, mz = -3.0e38f, mw = -3.0e38f;
    #pragma unroll
    for (int dr = 0; dr < 3; dr++) {
        int r = 2 * i - 1 + dr;
        if (r < 0 || r >= HI) continue;
        #pragma unroll
        for (int dc = 0; dc < 3; dc++) {
            int cc = 2 * j - 1 + dc;
            if (cc < 0 || cc >= HI) continue;
            float4 v = *(const float4*)(base + (size_t)(r * HI + cc) * 256);
            mx = fmaxf(mx, v.x); my = fmaxf(my, v.y);
            mz = fmaxf(mz, v.z); mw = fmaxf(mw, v.w);
        }
    }
    float4 o; o.x = mx; o.y = my; o.z = mz; o.w = mw;
    *(float4*)(out + (size_t)idx * 4) = o;
}

// ---------------- rearrange p2T [16][196][256] -> xg [8*4][98][256] (row copy) ----------------
__global__ __launch_bounds__(256) void k_rearr_xg_t(const float* __restrict__ p2, float* __restrict__ xg) {
    int t = threadIdx.x;
    int r = blockIdx.x * 4 + (t >> 6);           // over 3136 rows
    int c4 = (t & 63) << 2;
    int gihi = r / 98, n = r % 98;
    int b = gihi >> 2, gi = gihi & 3;
    int m = n / 49, rr = n % 49, w1 = rr / 7, w2 = rr % 7;
    int X = (gi >> 1) * 7 + w1, Y = (gi & 1) * 7 + w2;
    size_t src = ((size_t)((b * 2 + m) * 196 + X * 14 + Y)) * 256;
    *(float4*)(xg + (size_t)r * 256 + c4) = *(const float4*)(p2 + src + c4);
}

// ---------------- global attention ----------------
__global__ __launch_bounds__(256, 2) void k_gattn(const float* __restrict__ xg, float* __restrict__ qpart) {
    int rt = blockIdx.x, gi = blockIdx.y, b = blockIdx.z;
    __shared__ float A_l[98][68];
    __shared__ float S_l[14][100];
    int t = threadIdx.x;
    const float* Ab = xg + (size_t)(b * 4 + gi) * 98 * 256;
    int ti = t >> 5, tj = t & 31;
    int i1c = (ti + 8 < 14) ? ti + 8 : 13;
    int jc[4];
    #pragma unroll
    for (int jj = 0; jj < 4; jj++) { int j = tj + 32 * jj; jc[jj] = (j < 98) ? j : 97; }
    float accS[2][4] = {};
    for (int ch = 0; ch < 4; ch++) {
        __syncthreads();
        for (int u = t; u < 1568; u += 256) {
            int row = u >> 4, c4 = (u & 15) << 2;
            *(float4*)&A_l[row][c4] = *(const float4*)(Ab + row * 256 + ch * 64 + c4);
        }
        __syncthreads();
        for (int c4 = 0; c4 < 64; c4 += 4) {
            float4 ak[4];
            #pragma unroll
            for (int jj = 0; jj < 4; jj++) ak[jj] = *(const float4*)&A_l[jc[jj]][c4];
            float4 aq0 = *(const float4*)&A_l[rt * 14 + ti][c4];
            float4 aq1 = *(const float4*)&A_l[rt * 14 + i1c][c4];
            #pragma unroll
            for (int jj = 0; jj < 4; jj++) {
                accS[0][jj] += aq0.x * ak[jj].x + aq0.y * ak[jj].y + aq0.z * ak[jj].z + aq0.w * ak[jj].w;
                accS[1][jj] += aq1.x * ak[jj].x + aq1.y * ak[jj].y + aq1.z * ak[jj].z + aq1.w * ak[jj].w;
            }
        }
    }
    #pragma unroll
    for (int ii = 0; ii < 2; ii++) {
        int il = ti + 8 * ii;
        if (il < 14) {
            #pragma unroll
            for (int jj = 0; jj < 4; jj++) {
                int j = tj + 32 * jj;
                if (j < 98) S_l[il][j] = accS[ii][jj];
            }
        }
    }
    __syncthreads();
    {
        int g = t >> 4, l = t & 15;
        if (g < 14) {
            float mx = -3.0e38f;
            for (int jj = 0; jj < 7; jj++) { int j = l + 16 * jj; if (j < 98) mx = fmaxf(mx, S_l[g][j]); }
            #pragma unroll
            for (int off = 8; off > 0; off >>= 1) mx = fmaxf(mx, __shfl_xor(mx, off, 16));
            float sum = 0.f;
            for (int jj = 0; jj < 7; jj++) {
                int j = l + 16 * jj;
                if (j < 98) { float e = __expf(S_l[g][j] - mx); S_l[g][j] = e; sum += e; }
            }
            #pragma unroll
            for (int off = 8; off > 0; off >>= 1) sum += __shfl_xor(sum, off, 16);
            float inv = 0.0625f / sum;
            for (int jj = 0; jj < 7; jj++) { int j = l + 16 * jj; if (j < 98) S_l[g][j] *= inv; }
        }
    }
    __syncthreads();
    int ti2 = t >> 4, tc2 = t & 15;
    int rowv = (ti2 < 14);
    int ti2c = rowv ? ti2 : 13;
    size_t qrow = ((size_t)(b * 4 + gi) * 98 + rt * 14 + ti2c) * 256;
    for (int ch = 0; ch < 4; ch++) {
        __syncthreads();
        for (int u = t; u < 1568; u += 256) {
            int row = u >> 4, c4 = (u & 15) << 2;
            *(float4*)&A_l[row][c4] = *(const float4*)(Ab + row * 256 + ch * 64 + c4);
        }
        __syncthreads();
        float4 acc = make_float4(0.f, 0.f, 0.f, 0.f);
        for (int j0 = 0; j0 < 96; j0 += 4) {
            float s4[4];
            *(float4*)s4 = *(const float4*)&S_l[ti2c][j0];
            #pragma unroll
            for (int jj = 0; jj < 4; jj++) {
                float4 a = *(const float4*)&A_l[j0 + jj][tc2 * 4];
                acc.x += s4[jj] * a.x; acc.y += s4[jj] * a.y; acc.z += s4[jj] * a.z; acc.w += s4[jj] * a.w;
            }
        }
        #pragma unroll
        for (int j = 96; j < 98; j++) {
            float sv = S_l[ti2c][j];
            float4 a = *(const float4*)&A_l[j][tc2 * 4];
            acc.x += sv * a.x; acc.y += sv * a.y; acc.z += sv * a.z; acc.w += sv * a.w;
        }
        if (rowv) *(float4*)(qpart + qrow + ch * 64 + tc2 * 4) = acc;
    }
}

// ---------------- mean over 4 grid slices -> q_global bf16, layout [b][h][row][32] ----------------
__global__ __launch_bounds__(256) void k_qmean(const float* __restrict__ qpart, u16* __restrict__ qg) {
    int u = blockIdx.x * 256 + threadIdx.x;
    int b = u / 6272, r = u % 6272;
    const float* bp = qpart + (size_t)b * 100352 + (size_t)r * 4;
    float4 a0 = *(const float4*)(bp);
    float4 a1 = *(const float4*)(bp + 25088);
    float4 a2 = *(const float4*)(bp + 50176);
    float4 a3 = *(const float4*)(bp + 75264);
    ushort4 o;
    o.x = f2b(0.25f * (a0.x + a1.x + a2.x + a3.x));
    o.y = f2b(0.25f * (a0.y + a1.y + a2.y + a3.y));
    o.z = f2b(0.25f * (a0.z + a1.z + a2.z + a3.z));
    o.w = f2b(0.25f * (a0.w + a1.w + a2.w + a3.w));
    int row = r >> 6;
    int c = (r & 63) * 4;
    int h = c >> 5, d0 = c & 31;
    *(ushort4*)(qg + ((size_t)(b * 8 + h) * 98 + row) * 32 + d0) = o;
}

extern "C" void kernel_launch(void* const* d_in, const int* in_sizes, int n_in,
                              void* d_out, int out_size, void* d_ws, size_t ws_size,
                              hipStream_t stream) {
    const float* x      = (const float*)d_in[0];
    const float* qkv_w  = (const float*)d_in[1];
    const float* qkv_b  = (const float*)d_in[2];
    const float* to_out = (const float*)d_in[3];
    const float* rpe    = (const float*)d_in[4];
    const float* fe1_dw = (const float*)d_in[5];
    const float* fe1_s1 = (const float*)d_in[6];
    const float* fe1_s2 = (const float*)d_in[7];
    const float* fe1_pw = (const float*)d_in[8];
    const float* fe2_dw = (const float*)d_in[9];
    const float* fe2_s1 = (const float*)d_in[10];
    const float* fe2_s2 = (const float*)d_in[11];
    const float* fe2_pw = (const float*)d_in[12];

    float* ws   = (float*)d_ws;
    float* xg0  = ws;                         // [16][3136][256] fp32 (NHWC)
    u16*   ybuf = (u16*)(ws + 12845056);      // [16][HW][256] bf16 (NHWC)
    u16*   kvbf = (u16*)ws;                   // [2][8][50176][32] bf16 (phase B)
    u16*   aobf = (u16*)(ws + 12845056);      // [50176][256] bf16 (phase B)
    float* p1   = ws + 32112640;              // [16][784][256] fp32
    float* p2   = ws + 35323904;              // [16][196][256] fp32
    float* xgb  = ws + 36126720;              // [8*4][98][256] fp32
    float* qprt = ws + 36929536;              // [8][4][98][256]
    u16*   qgbf = (u16*)(ws + 37732352);      // [8][8][98][32] bf16
    float* dwt1 = ws + 37832704;              // [9][256] fp32 (in qgbf..wqt gap)
    float* dwt2 = ws + 37835008;              // [9][256] fp32
    u16*   wqt  = (u16*)(ws + 37933056);      // [512][256] bf16
    u16*   wot  = (u16*)(ws + 37998592);      // [256][256] bf16
    float* sbuf = ws + 38031360;              // [16][256]
    float* tbuf = ws + 38035456;              // [16][64]
    float* ubuf = ws + 38036480;              // [16][256]
    u16*   pwb1 = (u16*)(ws + 38040576);      // [256][256] bf16
    u16*   pwb2 = (u16*)(ws + 38073344);      // [256][256] bf16
    u16*   pwsc = (u16*)(ws + 38106112);      // [16][256][256] bf16
    float* biasf = qprt;                      // [8][98][112] fp32, aliases qprt (dead after k_qmean)

    k_prep_w<<<1298, 256, 0, stream>>>(qkv_w, to_out, fe1_pw, fe2_pw, fe1_dw, fe2_dw,
                                       wqt, wot, pwb1, pwb2, dwt1, dwt2);
    // ---- prep: x -> xg0 (NHWC) ----
    k_prep_xg<<<12544, 256, 0, stream>>>(x, xg0);
    // ---- global query path (NHWC) ----
    k_dwconv_t<3136, 56><<<6272, 256, 0, stream>>>(xg0, dwt1, ybuf);
    hipMemsetAsync(sbuf, 0, 16 * 256 * sizeof(float), stream);
    k_chanmean_t<3136><<<dim3(16, 16), 256, 0, stream>>>(ybuf, sbuf);
    k_se1<<<4, 256, 0, stream>>>(sbuf, fe1_s1, tbuf, 1.0f / 3136.0f);
    k_se2<<<16, 256, 0, stream>>>(tbuf, fe1_s2, ubuf);
    k_scale_w<<<4096, 256, 0, stream>>>(pwb1, ubuf, pwsc);
    k_pwconv_mfma_t<3136><<<800, 256, 0, stream>>>(ybuf, pwsc, xg0);
    k_maxpool_t<56><<<3136, 256, 0, stream>>>(xg0, p1);
    k_dwconv_t<784, 28><<<1568, 256, 0, stream>>>(p1, dwt2, ybuf);
    hipMemsetAsync(sbuf, 0, 16 * 256 * sizeof(float), stream);
    k_chanmean_t<784><<<dim3(16, 16), 256, 0, stream>>>(ybuf, sbuf);
    k_se1<<<4, 256, 0, stream>>>(sbuf, fe2_s1, tbuf, 1.0f / 784.0f);
    k_se2<<<16, 256, 0, stream>>>(tbuf, fe2_s2, ubuf);
    k_scale_w<<<4096, 256, 0, stream>>>(pwb2, ubuf, pwsc);
    k_pwconv_mfma_t<784><<<224, 256, 0, stream>>>(ybuf, pwsc, p1);
    k_maxpool_t<28><<<784, 256, 0, stream>>>(p1, p2);
    k_rearr_xg_t<<<784, 256, 0, stream>>>(p2, xgb);
    k_gattn<<<dim3(7, 4, 8), 256, 0, stream>>>(xgb, qprt);
    k_qmean<<<196, 256, 0, stream>>>(qprt, qgbf);
    // biasf precompute (aliases qprt — qprt is dead after k_qmean)
    k_bias<<<343, 256, 0, stream>>>(rpe, biasf);
    // ---- window attention path (all MFMA) ----
    k_gemm_qkv<<<dim3(392, 4), 256, 0, stream>>>(x, wqt, qkv_b, kvbf);
    k_attn_mfma<<<dim3(512, 8), 256, 0, stream>>>(kvbf, qgbf, biasf, aobf);
    k_gemm_toout<<<dim3(392, 2), 256, 0, stream>>>(aobf, wot, (float*)d_out);
}

// Round 14
// 366.377 us; speedup vs baseline: 1.0464x; 1.0464x over previous
//
#include <hip/hip_runtime.h>

// WindowAttentionGlobal on MI355X — round 21: REVERT to round-19 config.
// Round-20 post-mortem: staging qkv's A from fp32 x REGRESSED (370->383):
// A is read by 4 n0-blocks, so inlining the conversion quadrupled it and
// doubled A-side read traffic (200MB vs 100MB) for a 50MB saving. Lesson:
// materialize compact operands that get re-read K times. This is the best
// measured configuration (370.0us): tap-shared dwconv, bias precompute,
// swapped-QKT attn, head-major KVQ layouts, XCD swizzles, fused prep.

#define DEV static __device__ __forceinline__
typedef unsigned short u16;
typedef unsigned int u32;
typedef __attribute__((ext_vector_type(8))) short short8;
typedef __attribute__((ext_vector_type(4))) float f32x4;

DEV float b2f(u16 s) { union { u32 i; float f; } u; u.i = ((u32)s) << 16; return u.f; }
DEV u16 f2b(float f) {
    union { float f; u32 i; } u; u.f = f;
    u32 x = u.i;
    return (u16)((x + 0x7fffu + ((x >> 16) & 1u)) >> 16);
}
DEV u16 f2b_hw(float f) {
    __bf16 b = (__bf16)f;
    return __builtin_bit_cast(u16, b);
}
DEV float gelu_f(float x) { return 0.5f * x * (1.0f + erff(x * 0.70710678118654752440f)); }

// row r (window order) -> x flat base offset
DEV size_t x_rowbase(int r) {
    int b_ = r / 98, n = r % 98;
    int bb = b_ >> 6, gxi = (b_ >> 3) & 7, gyi = b_ & 7;
    int m = n / 49, rr = n % 49, w1 = rr / 7, w2 = rr % 7;
    return (((((size_t)(bb * 2 + m) * 8 + gxi) * 8 + gyi) * 7 + w1) * 7 + w2) * 256;
}

// ---------------- fused prep: linear x read -> xbf (window order) + xg0 (NHWC) ----------------
__global__ __launch_bounds__(256) void k_prep_both(const float* __restrict__ x, u16* __restrict__ xbf,
                                                   float* __restrict__ xg0) {
    int t = threadIdx.x;
    int s = blockIdx.x * 4 + (t >> 6);           // x-linear row, 0..50175
    int c4 = (t & 63) << 2;
    int w2 = s % 7, t1 = s / 7;
    int w1 = t1 % 7, t2 = t1 / 7;
    int gy = t2 % 8, t3 = t2 / 8;
    int gx = t3 % 8, nm = t3 / 8;
    int m = nm & 1, bb = nm >> 1;
    int r  = (bb * 64 + gx * 8 + gy) * 98 + m * 49 + w1 * 7 + w2;
    int rg = nm * 3136 + (gx * 7 + w1) * 56 + gy * 7 + w2;
    float4 v = *(const float4*)(x + (size_t)s * 256 + c4);
    ushort4 o; o.x = f2b(v.x); o.y = f2b(v.y); o.z = f2b(v.z); o.w = f2b(v.w);
    *(ushort4*)(xbf + (size_t)r * 256 + c4) = o;
    *(float4*)(xg0 + (size_t)rg * 256 + c4) = v;
}

// ---------------- prep: weights to bf16 + dw transpose ----------------
__global__ __launch_bounds__(256) void k_prep_w(const float* __restrict__ wq, const float* __restrict__ wo,
                                                const float* __restrict__ pw1, const float* __restrict__ pw2,
                                                const float* __restrict__ dw1, const float* __restrict__ dw2,
                                                u16* __restrict__ wqt, u16* __restrict__ wot,
                                                u16* __restrict__ pwb1, u16* __restrict__ pwb2,
                                                float* __restrict__ dwt1, float* __restrict__ dwt2) {
    int bid = blockIdx.x, t = threadIdx.x;
    if (bid < 512) {
        wqt[bid * 256 + t] = f2b(wq[(size_t)t * 512 + bid]);
    } else if (bid < 768) {
        int n = bid - 512;
        wot[n * 256 + t] = f2b(wo[(size_t)t * 256 + n]);
    } else if (bid < 1024) {
        int n = bid - 768;
        pwb1[n * 256 + t] = f2b(pw1[(size_t)n * 256 + t]);
    } else if (bid < 1280) {
        int n = bid - 1024;
        pwb2[n * 256 + t] = f2b(pw2[(size_t)n * 256 + t]);
    } else if (bid < 1289) {
        int k = bid - 1280;
        dwt1[k * 256 + t] = dw1[t * 9 + k];
    } else {
        int k = bid - 1289;
        dwt2[k * 256 + t] = dw2[t * 9 + k];
    }
}

// ---------------- precompute attention bias: biasf[h][i][j] (j padded to 112, pad = -1e38) ----------------
__global__ __launch_bounds__(256) void k_bias(const float* __restrict__ rpe, float* __restrict__ biasf) {
    int u = blockIdx.x * 256 + threadIdx.x;      // 8*98*112 = 87808 exactly (343 blocks)
    int h = u / 10976, rem = u % 10976;
    int i = rem / 112, j = rem % 112;
    float v;
    if (j >= 98) {
        v = -1.0e38f;
    } else {
        int mi = (i >= 49), ri = i - 49 * mi, ai = ri / 7, bi = ri % 7;
        int mj = (j >= 49), rj = j - 49 * mj, aj = rj / 7, bj = rj % 7;
        int idx = ((mi - mj + 1) * 13 + (ai - aj + 6)) * 13 + (bi - bj + 6);
        v = rpe[idx * 8 + h];
    }
    biasf[u] = v;
}

// ---------------- MFMA GEMM core (A[M][256] @ Bt[N][256]^T), 128x128 tile ----------------
DEV void gemm_tile(const u16* __restrict__ A, const u16* __restrict__ Bt,
                   int r0, int n0, int t, f32x4 acc[4][4],
                   u16 (*A_l)[72], u16 (*B_l)[72]) {
    int w = t >> 6, l = t & 63;
    int quad = l >> 4, lm = l & 15;
    int wm = (w & 1) * 64, wn = (w >> 1) * 64;
    for (int k0 = 0; k0 < 256; k0 += 64) {
        __syncthreads();
        #pragma unroll
        for (int i = 0; i < 4; i++) {
            int u = t + (i << 8);
            int row = u >> 3, k8 = (u & 7) << 3;
            *(uint4*)&A_l[row][k8] = *(const uint4*)(A + (size_t)(r0 + row) * 256 + k0 + k8);
            *(uint4*)&B_l[row][k8] = *(const uint4*)(Bt + (size_t)(n0 + row) * 256 + k0 + k8);
        }
        __syncthreads();
        #pragma unroll
        for (int kk = 0; kk < 64; kk += 32) {
            short8 af[4], bf[4];
            #pragma unroll
            for (int i = 0; i < 4; i++) af[i] = *(const short8*)&A_l[wm + 16 * i + lm][kk + quad * 8];
            #pragma unroll
            for (int j = 0; j < 4; j++) bf[j] = *(const short8*)&B_l[wn + 16 * j + lm][kk + quad * 8];
            #pragma unroll
            for (int i = 0; i < 4; i++)
                #pragma unroll
                for (int j = 0; j < 4; j++)
                    acc[i][j] = __builtin_amdgcn_mfma_f32_16x16x32_bf16(af[i], bf[j], acc[i][j], 0, 0, 0);
        }
    }
}

// qkv GEMM — writes kv in [sel][head][row][32] layout
__global__ __launch_bounds__(256, 2) void k_gemm_qkv(const u16* __restrict__ A, const u16* __restrict__ Bt,
                                                     const float* __restrict__ bias, u16* __restrict__ C) {
    __shared__ u16 A_l[128][72];
    __shared__ u16 B_l[128][72];
    int r0 = blockIdx.x * 128, n0 = blockIdx.y * 128;
    int t = threadIdx.x;
    f32x4 acc[4][4] = {};
    gemm_tile(A, Bt, r0, n0, t, acc, A_l, B_l);
    int w = t >> 6, l = t & 63;
    int quad = l >> 4, lm = l & 15;
    int wm = (w & 1) * 64, wn = (w >> 1) * 64;
    float bj[4];
    #pragma unroll
    for (int j = 0; j < 4; j++) bj[j] = bias[n0 + wn + 16 * j + lm];
    #pragma unroll
    for (int i = 0; i < 4; i++) {
        int rbase = r0 + wm + 16 * i + quad * 4;
        #pragma unroll
        for (int reg = 0; reg < 4; reg++) {
            int row = rbase + reg;
            #pragma unroll
            for (int j = 0; j < 4; j++) {
                int c0 = n0 + wn + 16 * j;                  // 16-aligned, within one head slab
                int slab = c0 >> 5;                          // sel*8 + head
                int dd = c0 & 31;                            // 0 or 16
                C[((size_t)slab * 50176 + row) * 32 + dd + lm] = f2b(acc[i][j][reg] + bj[j]);
            }
        }
    }
}

// toout GEMM + permutation
__global__ __launch_bounds__(256, 2) void k_gemm_toout(const u16* __restrict__ A, const u16* __restrict__ Bt,
                                                       float* __restrict__ outp) {
    __shared__ u16 A_l[128][72];
    __shared__ u16 B_l[128][72];
    int r0 = blockIdx.x * 128, n0 = blockIdx.y * 128;
    int t = threadIdx.x;
    f32x4 acc[4][4] = {};
    gemm_tile(A, Bt, r0, n0, t, acc, A_l, B_l);
    int w = t >> 6, l = t & 63;
    int quad = l >> 4, lm = l & 15;
    int wm = (w & 1) * 64, wn = (w >> 1) * 64;
    #pragma unroll
    for (int i = 0; i < 4; i++) {
        int rbase = r0 + wm + 16 * i + quad * 4;
        #pragma unroll
        for (int reg = 0; reg < 4; reg++) {
            size_t ob = x_rowbase(rbase + reg);
            #pragma unroll
            for (int j = 0; j < 4; j++)
                outp[ob + n0 + wn + 16 * j + lm] = acc[i][j][reg];
        }
    }
}

// ---------------- per-image SE-scaled weights: pwsc[n][co][ci] = pw[co][ci]*u[n][ci] ----------------
__global__ __launch_bounds__(256) void k_scale_w(const u16* __restrict__ pwb, const float* __restrict__ ubuf,
                                                 u16* __restrict__ pwsc) {
    int b = blockIdx.x;              // 4096 = 16n * 256co
    int n = b >> 8, co = b & 255;
    int ci = threadIdx.x;
    pwsc[((size_t)b) * 256 + ci] = f2b(b2f(pwb[co * 256 + ci]) * ubuf[n * 256 + ci]);
}

// ---------------- MFMA pointwise conv (NHWC, 1D grid, XCD-chunked) ----------------
template<int HW>
__global__ __launch_bounds__(256, 2) void k_pwconv_mfma_t(const u16* __restrict__ yT, const u16* __restrict__ pwsc,
                                                          float* __restrict__ base) {
    __shared__ u16 A_l[128][72];
    __shared__ u16 B_l[128][72];
    const int PX = (HW + 127) >> 7;
    int cpx = gridDim.x >> 3;
    int bid = (blockIdx.x & 7) * cpx + (blockIdx.x >> 3);
    int c0 = (bid & 1) * 128;
    int rem = bid >> 1;
    int p0 = (rem % PX) * 128;
    int n  = rem / PX;
    int t = threadIdx.x;
    const u16* A = yT + (size_t)n * HW * 256;
    const u16* Bt = pwsc + (size_t)n * 65536;
    f32x4 acc[4][4] = {};
    gemm_tile(A, Bt, p0, c0, t, acc, A_l, B_l);   // OOB A rows read garbage -> discarded rows
    int w = t >> 6, l = t & 63;
    int quad = l >> 4, lm = l & 15;
    int wm = (w & 1) * 64, wn = (w >> 1) * 64;
    #pragma unroll
    for (int i = 0; i < 4; i++) {
        int pb = p0 + wm + 16 * i + quad * 4;
        #pragma unroll
        for (int reg = 0; reg < 4; reg++) {
            int p = pb + reg;
            if (p < HW) {
                size_t rowb = ((size_t)n * HW + p) * 256;
                #pragma unroll
                for (int j = 0; j < 4; j++)
                    base[rowb + c0 + wn + 16 * j + lm] += acc[i][j][reg];
            }
        }
    }
}

// ---------------- MFMA window attention per (window b_, head h), 4 waves ----------------
// kv: [sel(2)][head(8)][row(50176)][32], qg: [b(8)][head(8)][row(98)][32]
// Swapped QK^T: acc = mfma(K, Q) -> lane lm holds q-row (m0+lm); j = t6*16+quad*4+reg.
__global__ __launch_bounds__(256, 4) void k_attn_mfma(const u16* __restrict__ kv, const u16* __restrict__ qg,
                                                      const float* __restrict__ biasf, u16* __restrict__ ao) {
    __shared__ u16 K_l[112][40];
    __shared__ u16 Vt_l[32][136];
    __shared__ u16 P_l[4][16][136];
    int b_ = blockIdx.x, h = blockIdx.y;
    int bb = b_ >> 6;
    int t = threadIdx.x;

    const u16* kq = kv + ((size_t)h * 50176 + (size_t)b_ * 98) * 32;          // sel=0 slab
    const u16* kvv = kv + ((size_t)(8 + h) * 50176 + (size_t)b_ * 98) * 32;   // sel=1 slab
    const u16* qgn = qg + ((size_t)(bb * 8 + h) * 98) * 32;

    // K staging: contiguous 16B/lane loads
    for (int u = t; u < 392; u += 256) {
        int row = u >> 2, q8 = (u & 3) << 3;
        *(short8*)&K_l[row][q8] = *(const short8*)(kq + u * 8);
    }
    for (int u = t; u < 224; u += 256) {
        int row = 98 + (u >> 4), c2 = (u & 15) << 1;
        *(u32*)&K_l[row][c2] = 0;
    }
    // V staging: contiguous short8 loads, transposed scatter into Vt_l
    for (int u = t; u < 392; u += 256) {
        int j = u >> 2, c = u & 3;
        short8 v = *(const short8*)(kvv + u * 8);
        #pragma unroll
        for (int e = 0; e < 8; e++) Vt_l[c * 8 + e][j] = (u16)v[e];
    }
    for (int u = t; u < 1216; u += 256) {
        int d = u / 38, c = 98 + u % 38;
        Vt_l[d][c] = 0;
    }
    for (int u = t; u < 1536; u += 256) {
        int wv = u / 384, rem = u % 384;
        P_l[wv][rem / 24][112 + rem % 24] = 0;
    }
    __syncthreads();

    int w = t >> 6, l = t & 63;
    int quad = l >> 4, lm = l & 15;
    const float scale = 0.17677669529663688f;

    #pragma unroll
    for (int half = 0; half < 2; half++) {
        int mt = w + 4 * half;
        if (mt >= 7) break;
        int m0 = mt * 16;
        int qrow = m0 + lm; qrow = (qrow < 98) ? qrow : 97;
        // bias: i = qrow (lane-local), j = t6*16 + quad*4 + reg -> 7 float4 loads
        const float* bp = biasf + (size_t)(h * 98 + qrow) * 112 + quad * 4;
        f32x4 b4[7];
        #pragma unroll
        for (int t6 = 0; t6 < 7; t6++) b4[t6] = *(const f32x4*)(bp + t6 * 16);
        short8 aq = *(const short8*)(qgn + qrow * 32 + quad * 8);
        f32x4 acc[7] = {};
        #pragma unroll
        for (int t6 = 0; t6 < 7; t6++) {
            short8 bk = *(const short8*)&K_l[t6 * 16 + lm][quad * 8];
            acc[t6] = __builtin_amdgcn_mfma_f32_16x16x32_bf16(bk, aq, acc[t6], 0, 0, 0);  // swapped
        }
        // softmax over lane-local row (28 values) + 2-shuffle cross-quad reduce
        float mx = -3.0e38f;
        #pragma unroll
        for (int t6 = 0; t6 < 7; t6++) {
            #pragma unroll
            for (int reg = 0; reg < 4; reg++) {
                float s = acc[t6][reg] * scale + b4[t6][reg];
                acc[t6][reg] = s;
                mx = fmaxf(mx, s);
            }
        }
        mx = fmaxf(mx, __shfl_xor(mx, 16));
        mx = fmaxf(mx, __shfl_xor(mx, 32));
        float sum = 0.f;
        #pragma unroll
        for (int t6 = 0; t6 < 7; t6++) {
            #pragma unroll
            for (int reg = 0; reg < 4; reg++) {
                float e = __expf(acc[t6][reg] - mx);
                acc[t6][reg] = e; sum += e;
            }
        }
        sum += __shfl_xor(sum, 16);
        sum += __shfl_xor(sum, 32);
        float inv = 1.0f / sum;
        #pragma unroll
        for (int t6 = 0; t6 < 7; t6++) {
            ushort4 s4;
            s4.x = f2b_hw(acc[t6][0] * inv);
            s4.y = f2b_hw(acc[t6][1] * inv);
            s4.z = f2b_hw(acc[t6][2] * inv);
            s4.w = f2b_hw(acc[t6][3] * inv);
            *(ushort4*)&P_l[w][lm][t6 * 16 + quad * 4] = s4;
        }
        __builtin_amdgcn_s_waitcnt(0);   // lgkmcnt(0): P_l writes visible wave-locally
        short8 pa[4];
        #pragma unroll
        for (int kc = 0; kc < 4; kc++)
            pa[kc] = *(const short8*)&P_l[w][lm][kc * 32 + quad * 8];
        #pragma unroll
        for (int nt = 0; nt < 2; nt++) {
            f32x4 oacc = {};
            #pragma unroll
            for (int kc = 0; kc < 4; kc++) {
                short8 bv = *(const short8*)&Vt_l[nt * 16 + lm][kc * 32 + quad * 8];
                oacc = __builtin_amdgcn_mfma_f32_16x16x32_bf16(pa[kc], bv, oacc, 0, 0, 0);
            }
            #pragma unroll
            for (int reg = 0; reg < 4; reg++) {
                int orow = m0 + quad * 4 + reg;
                if (orow < 98)
                    ao[((size_t)(b_ * 98 + orow)) * 256 + h * 32 + nt * 16 + lm] = f2b_hw(oacc[reg]);
            }
        }
    }
}

// ---------------- depthwise 3x3 pad1 + GELU (NHWC, 2 pixels x 4ch/thread, XCD-swizzled) -> bf16 ----------------
template<int HW, int WW>
__global__ __launch_bounds__(256) void k_dwconv_t(const float* __restrict__ in, const float* __restrict__ dwT,
                                                  u16* __restrict__ out) {
    const int HP = HW / 2;                       // pixel pairs per image
    const int WP = WW / 2;
    int cpx = gridDim.x >> 3;
    int bid = (blockIdx.x & 7) * cpx + (blockIdx.x >> 3);
    int idx = bid * 256 + threadIdx.x;           // over 16*HP*64
    int c4 = (idx & 63) << 2;
    int pp = (idx >> 6) % HP;
    int n  = (idx >> 6) / HP;
    int i  = pp / WP, jp = (pp % WP) * 2;        // pixels (i,jp), (i,jp+1)
    const float* base = in + (size_t)n * HW * 256 + c4;
    f32x4 w0[3], w1[3], w2[3];
    #pragma unroll
    for (int dy = 0; dy < 3; dy++) {
        w0[dy] = *(const f32x4*)(dwT + (dy * 3 + 0) * 256 + c4);
        w1[dy] = *(const f32x4*)(dwT + (dy * 3 + 1) * 256 + c4);
        w2[dy] = *(const f32x4*)(dwT + (dy * 3 + 2) * 256 + c4);
    }
    f32x4 acc0 = {}, acc1 = {};
    #pragma unroll
    for (int dy = 0; dy < 3; dy++) {
        int y = i + dy - 1;
        if (y < 0 || y >= WW) continue;
        const float* rowb = base + (size_t)(y * WW) * 256;
        f32x4 v1 = *(const f32x4*)(rowb + (size_t)jp * 256);
        f32x4 v2 = *(const f32x4*)(rowb + (size_t)(jp + 1) * 256);
        f32x4 v0 = (jp > 0) ? *(const f32x4*)(rowb + (size_t)(jp - 1) * 256) : (f32x4){};
        f32x4 v3 = (jp + 2 < WW) ? *(const f32x4*)(rowb + (size_t)(jp + 2) * 256) : (f32x4){};
        acc0 += v0 * w0[dy] + v1 * w1[dy] + v2 * w2[dy];
        acc1 += v1 * w0[dy] + v2 * w1[dy] + v3 * w2[dy];
    }
    ushort4 o0, o1;
    o0.x = f2b(gelu_f(acc0[0])); o0.y = f2b(gelu_f(acc0[1]));
    o0.z = f2b(gelu_f(acc0[2])); o0.w = f2b(gelu_f(acc0[3]));
    o1.x = f2b(gelu_f(acc1[0])); o1.y = f2b(gelu_f(acc1[1]));
    o1.z = f2b(gelu_f(acc1[2])); o1.w = f2b(gelu_f(acc1[3]));
    size_t ob = ((size_t)n * HW + (size_t)i * WW + jp) * 256 + c4;
    *(ushort4*)(out + ob) = o0;
    *(ushort4*)(out + ob + 256) = o1;
}

// ---------------- channel sums (NHWC): sbuf[n][c] += partial (round-16 form) ----------------
template<int HW>
__global__ __launch_bounds__(256) void k_chanmean_t(const u16* __restrict__ y, float* __restrict__ sbuf) {
    int n = blockIdx.x, sl = blockIdx.y;         // 16 slices
    int c = threadIdx.x;
    const int PP = HW / 16;
    const u16* base = y + ((size_t)n * HW + sl * PP) * 256 + c;
    float s = 0.f;
    for (int p = 0; p < PP; p++) s += b2f(base[(size_t)p * 256]);
    atomicAdd(&sbuf[n * 256 + c], s);
}

// ---------------- SE MLP (1/HW folded into se1) ----------------
__global__ __launch_bounds__(256) void k_se1(const float* __restrict__ sbuf, const float* __restrict__ se1,
                                             float* __restrict__ tbuf, float invHW) {
    int o = blockIdx.x * 256 + threadIdx.x;
    int n = o >> 6, j = o & 63;
    const float* srow = sbuf + n * 256;
    float acc = 0.f;
    for (int c = 0; c < 256; c++) acc += srow[c] * se1[c * 64 + j];
    tbuf[o] = gelu_f(acc * invHW);
}
__global__ __launch_bounds__(256) void k_se2(const float* __restrict__ tbuf, const float* __restrict__ se2,
                                             float* __restrict__ ubuf) {
    int o = blockIdx.x * 256 + threadIdx.x;
    int n = o >> 8, co = o & 255;
    const float* trow = tbuf + n * 64;
    float acc = 0.f;
    for (int j = 0; j < 64; j++) acc += trow[j] * se2[j * 256 + co];
    ubuf[o] = 1.0f / (1.0f + __expf(-acc));
}

// ---------------- maxpool 3x3 s2 p1 (NHWC, float4/thread, XCD-swizzled) ----------------
template<int HI>
__global__ __launch_bounds__(256) void k_maxpool_t(const float* __restrict__ in, float* __restrict__ out) {
    const int HO = HI / 2;
    int cpx = gridDim.x >> 3;
    int bid = (blockIdx.x & 7) * cpx + (blockIdx.x >> 3);
    int idx = bid * 256 + threadIdx.x;           // over 16*HO*HO*64
    int c4 = (idx & 63) << 2;
    int pp = (idx >> 6) % (HO * HO);
    int n = (idx >> 6) / (HO * HO);
    int j = pp % HO, i = pp / HO;
    const float* base = in + (size_t)n * HI * HI * 256 + c4;
    float mx = -3.0e38f, my = -3.0e38f, mz = -3.0e38f, mw = -3.0e38f;
    #pragma unroll
    for (int dr = 0; dr < 3; dr++) {
        int r = 2 * i - 1 + dr;
        if (r < 0 || r >= HI) continue;
        #pragma unroll
        for (int dc = 0; dc < 3; dc++) {
            int cc = 2 * j - 1 + dc;
            if (cc < 0 || cc >= HI) continue;
            float4 v = *(const float4*)(base + (size_t)(r * HI + cc) * 256);
            mx = fmaxf(mx, v.x); my = fmaxf(my, v.y);
            mz = fmaxf(mz, v.z); mw = fmaxf(mw, v.w);
        }
    }
    float4 o; o.x = mx; o.y = my; o.z = mz; o.w = mw;
    *(float4*)(out + (size_t)idx * 4) = o;
}

// ---------------- rearrange p2T [16][196][256] -> xg [8*4][98][256] (row copy) ----------------
__global__ __launch_bounds__(256) void k_rearr_xg_t(const float* __restrict__ p2, float* __restrict__ xg) {
    int t = threadIdx.x;
    int r = blockIdx.x * 4 + (t >> 6);           // over 3136 rows
    int c4 = (t & 63) << 2;
    int gihi = r / 98, n = r % 98;
    int b = gihi >> 2, gi = gihi & 3;
    int m = n / 49, rr = n % 49, w1 = rr / 7, w2 = rr % 7;
    int X = (gi >> 1) * 7 + w1, Y = (gi & 1) * 7 + w2;
    size_t src = ((size_t)((b * 2 + m) * 196 + X * 14 + Y)) * 256;
    *(float4*)(xg + (size_t)r * 256 + c4) = *(const float4*)(p2 + src + c4);
}

// ---------------- global attention ----------------
__global__ __launch_bounds__(256, 2) void k_gattn(const float* __restrict__ xg, float* __restrict__ qpart) {
    int rt = blockIdx.x, gi = blockIdx.y, b = blockIdx.z;
    __shared__ float A_l[98][68];
    __shared__ float S_l[14][100];
    int t = threadIdx.x;
    const float* Ab = xg + (size_t)(b * 4 + gi) * 98 * 256;
    int ti = t >> 5, tj = t & 31;
    int i1c = (ti + 8 < 14) ? ti + 8 : 13;
    int jc[4];
    #pragma unroll
    for (int jj = 0; jj < 4; jj++) { int j = tj + 32 * jj; jc[jj] = (j < 98) ? j : 97; }
    float accS[2][4] = {};
    for (int ch = 0; ch < 4; ch++) {
        __syncthreads();
        for (int u = t; u < 1568; u += 256) {
            int row = u >> 4, c4 = (u & 15) << 2;
            *(float4*)&A_l[row][c4] = *(const float4*)(Ab + row * 256 + ch * 64 + c4);
        }
        __syncthreads();
        for (int c4 = 0; c4 < 64; c4 += 4) {
            float4 ak[4];
            #pragma unroll
            for (int jj = 0; jj < 4; jj++) ak[jj] = *(const float4*)&A_l[jc[jj]][c4];
            float4 aq0 = *(const float4*)&A_l[rt * 14 + ti][c4];
            float4 aq1 = *(const float4*)&A_l[rt * 14 + i1c][c4];
            #pragma unroll
            for (int jj = 0; jj < 4; jj++) {
                accS[0][jj] += aq0.x * ak[jj].x + aq0.y * ak[jj].y + aq0.z * ak[jj].z + aq0.w * ak[jj].w;
                accS[1][jj] += aq1.x * ak[jj].x + aq1.y * ak[jj].y + aq1.z * ak[jj].z + aq1.w * ak[jj].w;
            }
        }
    }
    #pragma unroll
    for (int ii = 0; ii < 2; ii++) {
        int il = ti + 8 * ii;
        if (il < 14) {
            #pragma unroll
            for (int jj = 0; jj < 4; jj++) {
                int j = tj + 32 * jj;
                if (j < 98) S_l[il][j] = accS[ii][jj];
            }
        }
    }
    __syncthreads();
    {
        int g = t >> 4, l = t & 15;
        if (g < 14) {
            float mx = -3.0e38f;
            for (int jj = 0; jj < 7; jj++) { int j = l + 16 * jj; if (j < 98) mx = fmaxf(mx, S_l[g][j]); }
            #pragma unroll
            for (int off = 8; off > 0; off >>= 1) mx = fmaxf(mx, __shfl_xor(mx, off, 16));
            float sum = 0.f;
            for (int jj = 0; jj < 7; jj++) {
                int j = l + 16 * jj;
                if (j < 98) { float e = __expf(S_l[g][j] - mx); S_l[g][j] = e; sum += e; }
            }
            #pragma unroll
            for (int off = 8; off > 0; off >>= 1) sum += __shfl_xor(sum, off, 16);
            float inv = 0.0625f / sum;
            for (int jj = 0; jj < 7; jj++) { int j = l + 16 * jj; if (j < 98) S_l[g][j] *= inv; }
        }
    }
    __syncthreads();
    int ti2 = t >> 4, tc2 = t & 15;
    int rowv = (ti2 < 14);
    int ti2c = rowv ? ti2 : 13;
    size_t qrow = ((size_t)(b * 4 + gi) * 98 + rt * 14 + ti2c) * 256;
    for (int ch = 0; ch < 4; ch++) {
        __syncthreads();
        for (int u = t; u < 1568; u += 256) {
            int row = u >> 4, c4 = (u & 15) << 2;
            *(float4*)&A_l[row][c4] = *(const float4*)(Ab + row * 256 + ch * 64 + c4);
        }
        __syncthreads();
        float4 acc = make_float4(0.f, 0.f, 0.f, 0.f);
        for (int j0 = 0; j0 < 96; j0 += 4) {
            float s4[4];
            *(float4*)s4 = *(const float4*)&S_l[ti2c][j0];
            #pragma unroll
            for (int jj = 0; jj < 4; jj++) {
                float4 a = *(const float4*)&A_l[j0 + jj][tc2 * 4];
                acc.x += s4[jj] * a.x; acc.y += s4[jj] * a.y; acc.z += s4[jj] * a.z; acc.w += s4[jj] * a.w;
            }
        }
        #pragma unroll
        for (int j = 96; j < 98; j++) {
            float sv = S_l[ti2c][j];
            float4 a = *(const float4*)&A_l[j][tc2 * 4];
            acc.x += sv * a.x; acc.y += sv * a.y; acc.z += sv * a.z; acc.w += sv * a.w;
        }
        if (rowv) *(float4*)(qpart + qrow + ch * 64 + tc2 * 4) = acc;
    }
}

// ---------------- mean over 4 grid slices -> q_global bf16, layout [b][h][row][32] ----------------
__global__ __launch_bounds__(256) void k_qmean(const float* __restrict__ qpart, u16* __restrict__ qg) {
    int u = blockIdx.x * 256 + threadIdx.x;
    int b = u / 6272, r = u % 6272;
    const float* bp = qpart + (size_t)b * 100352 + (size_t)r * 4;
    float4 a0 = *(const float4*)(bp);
    float4 a1 = *(const float4*)(bp + 25088);
    float4 a2 = *(const float4*)(bp + 50176);
    float4 a3 = *(const float4*)(bp + 75264);
    ushort4 o;
    o.x = f2b(0.25f * (a0.x + a1.x + a2.x + a3.x));
    o.y = f2b(0.25f * (a0.y + a1.y + a2.y + a3.y));
    o.z = f2b(0.25f * (a0.z + a1.z + a2.z + a3.z));
    o.w = f2b(0.25f * (a0.w + a1.w + a2.w + a3.w));
    int row = r >> 6;
    int c = (r & 63) * 4;
    int h = c >> 5, d0 = c & 31;
    *(ushort4*)(qg + ((size_t)(b * 8 + h) * 98 + row) * 32 + d0) = o;
}

extern "C" void kernel_launch(void* const* d_in, const int* in_sizes, int n_in,
                              void* d_out, int out_size, void* d_ws, size_t ws_size,
                              hipStream_t stream) {
    const float* x      = (const float*)d_in[0];
    const float* qkv_w  = (const float*)d_in[1];
    const float* qkv_b  = (const float*)d_in[2];
    const float* to_out = (const float*)d_in[3];
    const float* rpe    = (const float*)d_in[4];
    const float* fe1_dw = (const float*)d_in[5];
    const float* fe1_s1 = (const float*)d_in[6];
    const float* fe1_s2 = (const float*)d_in[7];
    const float* fe1_pw = (const float*)d_in[8];
    const float* fe2_dw = (const float*)d_in[9];
    const float* fe2_s1 = (const float*)d_in[10];
    const float* fe2_s2 = (const float*)d_in[11];
    const float* fe2_pw = (const float*)d_in[12];

    float* ws   = (float*)d_ws;
    float* xg0  = ws;                         // [16][3136][256] fp32 (NHWC)
    u16*   ybuf = (u16*)(ws + 12845056);      // [16][HW][256] bf16 (NHWC)
    u16*   kvbf = (u16*)ws;                   // [2][8][50176][32] bf16 (phase B)
    u16*   aobf = (u16*)(ws + 12845056);      // [50176][256] bf16 (phase B)
    u16*   xbf  = (u16*)(ws + 25690112);      // [50176][256] bf16
    float* p1   = ws + 32112640;              // [16][784][256] fp32
    float* p2   = ws + 35323904;              // [16][196][256] fp32
    float* xgb  = ws + 36126720;              // [8*4][98][256] fp32
    float* qprt = ws + 36929536;              // [8][4][98][256]
    u16*   qgbf = (u16*)(ws + 37732352);      // [8][8][98][32] bf16
    float* dwt1 = ws + 37832704;              // [9][256] fp32 (in qgbf..wqt gap)
    float* dwt2 = ws + 37835008;              // [9][256] fp32
    u16*   wqt  = (u16*)(ws + 37933056);      // [512][256] bf16
    u16*   wot  = (u16*)(ws + 37998592);      // [256][256] bf16
    float* sbuf = ws + 38031360;              // [16][256]
    float* tbuf = ws + 38035456;              // [16][64]
    float* ubuf = ws + 38036480;              // [16][256]
    u16*   pwb1 = (u16*)(ws + 38040576);      // [256][256] bf16
    u16*   pwb2 = (u16*)(ws + 38073344);      // [256][256] bf16
    u16*   pwsc = (u16*)(ws + 38106112);      // [16][256][256] bf16
    float* biasf = qprt;                      // [8][98][112] fp32, aliases qprt (dead after k_qmean)

    k_prep_w<<<1298, 256, 0, stream>>>(qkv_w, to_out, fe1_pw, fe2_pw, fe1_dw, fe2_dw,
                                       wqt, wot, pwb1, pwb2, dwt1, dwt2);
    // ---- fused prep: x -> xbf (window order) + xg0 (NHWC) ----
    k_prep_both<<<12544, 256, 0, stream>>>(x, xbf, xg0);
    // ---- global query path (NHWC) ----
    k_dwconv_t<3136, 56><<<6272, 256, 0, stream>>>(xg0, dwt1, ybuf);
    hipMemsetAsync(sbuf, 0, 16 * 256 * sizeof(float), stream);
    k_chanmean_t<3136><<<dim3(16, 16), 256, 0, stream>>>(ybuf, sbuf);
    k_se1<<<4, 256, 0, stream>>>(sbuf, fe1_s1, tbuf, 1.0f / 3136.0f);
    k_se2<<<16, 256, 0, stream>>>(tbuf, fe1_s2, ubuf);
    k_scale_w<<<4096, 256, 0, stream>>>(pwb1, ubuf, pwsc);
    k_pwconv_mfma_t<3136><<<800, 256, 0, stream>>>(ybuf, pwsc, xg0);
    k_maxpool_t<56><<<3136, 256, 0, stream>>>(xg0, p1);
    k_dwconv_t<784, 28><<<1568, 256, 0, stream>>>(p1, dwt2, ybuf);
    hipMemsetAsync(sbuf, 0, 16 * 256 * sizeof(float), stream);
    k_chanmean_t<784><<<dim3(16, 16), 256, 0, stream>>>(ybuf, sbuf);
    k_se1<<<4, 256, 0, stream>>>(sbuf, fe2_s1, tbuf, 1.0f / 784.0f);
    k_se2<<<16, 256, 0, stream>>>(tbuf, fe2_s2, ubuf);
    k_scale_w<<<4096, 256, 0, stream>>>(pwb2, ubuf, pwsc);
    k_pwconv_mfma_t<784><<<224, 256, 0, stream>>>(ybuf, pwsc, p1);
    k_maxpool_t<28><<<784, 256, 0, stream>>>(p1, p2);
    k_rearr_xg_t<<<784, 256, 0, stream>>>(p2, xgb);
    k_gattn<<<dim3(7, 4, 8), 256, 0, stream>>>(xgb, qprt);
    k_qmean<<<196, 256, 0, stream>>>(qprt, qgbf);
    // biasf precompute (aliases qprt — qprt is dead after k_qmean)
    k_bias<<<343, 256, 0, stream>>>(rpe, biasf);
    // ---- window attention path (all MFMA) ----
    k_gemm_qkv<<<dim3(392, 4), 256, 0, stream>>>(xbf, wqt, qkv_b, kvbf);
    k_attn_mfma<<<dim3(512, 8), 256, 0, stream>>>(kvbf, qgbf, biasf, aobf);
    k_gemm_toout<<<dim3(392, 2), 256, 0, stream>>>(aobf, wot, (float*)d_out);
}